// Round 22
// baseline (107.010 us; speedup 1.0000x reference)
//
#include <hip/hip_runtime.h>
#include <math.h>

// Problem constants (B=4, T=2048, D_MODEL=512, H=8, HD=64)
#define TT   2048
#define DM   512
#define NH   8
#define HD   64
#define MM   8192          // B*T
#define EQKV 1536          // 3*DM
#define KVB  128           // attention key-tile (pair of 64-key parity halves)
#define NKT  (TT / KVB)    // 16

typedef __attribute__((ext_vector_type(4)))  float f32x4;
typedef __attribute__((ext_vector_type(16))) float f32x16;
typedef __attribute__((ext_vector_type(8)))  short s16x8;   // 8 bf16 = 4 VGPRs

#define MFMA16(a, b, c) __builtin_amdgcn_mfma_f32_16x16x32_bf16((a), (b), (c), 0, 0, 0)
#define MFMA32(a, b, c) __builtin_amdgcn_mfma_f32_32x32x16_bf16((a), (b), (c), 0, 0, 0)

__device__ __forceinline__ unsigned short f2bf(float f) {
    unsigned int u = __float_as_uint(f);
    u += 0x7FFFu + ((u >> 16) & 1);          // round-to-nearest-even
    return (unsigned short)(u >> 16);
}

// Hardware 2^x (single v_exp_f32) — libm exp2f expands to a slow precise
// sequence (r7: +17us VALU in attn; r9 confirmed the fix).
__device__ __forceinline__ float fexp2(float x) {
#if __has_builtin(__builtin_amdgcn_exp2f)
    return __builtin_amdgcn_exp2f(x);
#else
    float r; asm("v_exp_f32 %0, %1" : "=v"(r) : "v"(x)); return r;
#endif
}

// chunk XOR bits for [*][64]-short tiles (8 chunks of 8 shorts per row)
__device__ __forceinline__ int xb(int row) {
    return (row & 7) ^ (((row >> 3) & 3) << 1);
}
// swizzled short index, [rows][64] bf16 tile (GEMM staging)
__device__ __forceinline__ int swz(int row, int k) {
    return row * 64 + (k ^ (xb(row) << 3));
}
// swizzled short index, [rows][128] tile, 4-bit XOR -> conflict-free (r10: 0)
__device__ __forceinline__ int swzV(int row, int k) {
    return row * 128 + (k ^ ((row & 15) << 3));
}

// async global->LDS, 16 B per lane; lds base must be wave-uniform.
__device__ __forceinline__ void gl16(const unsigned short* g, short* l) {
    __builtin_amdgcn_global_load_lds(
        (const __attribute__((address_space(1))) unsigned int*)g,
        (__attribute__((address_space(3))) unsigned int*)l, 16, 0, 0);
}

// ---------------------------------------------------------------------------
// fp32 -> bf16 conversion prepass for x, w_qkv, w_out (counts in float4 units)
// ---------------------------------------------------------------------------
__global__ void cvt3(const float* __restrict__ s0, unsigned short* __restrict__ d0, int n0,
                     const float* __restrict__ s1, unsigned short* __restrict__ d1, int n1,
                     const float* __restrict__ s2, unsigned short* __restrict__ d2, int n2) {
    int i = blockIdx.x * blockDim.x + threadIdx.x;
    const int ntot = n0 + n1 + n2;
    const int stride = gridDim.x * blockDim.x;
    for (; i < ntot; i += stride) {
        const float* s; unsigned short* d; int j = i;
        if (j < n0) { s = s0; d = d0; }
        else if (j < n0 + n1) { s = s1; d = d1; j -= n0; }
        else { s = s2; d = d2; j -= n0 + n1; }
        const float4 v = ((const float4*)s)[j];
        ushort4 o;
        o.x = f2bf(v.x); o.y = f2bf(v.y); o.z = f2bf(v.z); o.w = f2bf(v.w);
        ((ushort4*)d)[j] = o;
    }
}

// ---------------------------------------------------------------------------
// QKV projection: qkv = x @ w_qkv^T + b_qkv, fused RoPE + head split.
// Q/K out: bf16 [B,H,T,64] (Q scaled by 0.125*log2e).
// V out: bf16 [B,H,64,T] TRANSPOSED with kappa(t) baked in.
// 128x128 tile, 8 waves. COUNTED-VMCNT 3-BUFFER PIPELINE (T4/m201): r21
// profile showed the __syncthreads vmcnt(0) drain exposes ~full HBM latency
// every K-iter (MfmaUtil 10%, VALU 14%). Raw s_barrier + s_waitcnt vmcnt(4)
// keeps the NEXT tile's 4 DMAs in flight across the barrier; 2 tiles always
// in flight (issue-to-use = 2 iters) covers the load latency entirely.
// LDS 96KB -> 1 block/CU (intentional: pipelining replaces TLP).
// ---------------------------------------------------------------------------
__launch_bounds__(512)
__global__ void gemm_qkv(const unsigned short* __restrict__ A,
                         const unsigned short* __restrict__ W,
                         const float* __restrict__ bias,
                         const float* __restrict__ rsin,
                         const float* __restrict__ rcos,
                         unsigned short* __restrict__ Qo,
                         unsigned short* __restrict__ Ko,
                         unsigned short* __restrict__ Vo) {
    __shared__ short As[3][128 * 64];
    __shared__ short Ws[3][128 * 64];

    const int tid = threadIdx.x;
    const int lane = tid & 63;
    const int wid = tid >> 6;            // 0..7
    const int wm = wid >> 2, wn = wid & 3;   // wave tile: rows wm*64, cols wn*32
    const int lr = lane & 15, lk = lane >> 4;
    const int m0 = blockIdx.y * 128, n0 = blockIdx.x * 128;

    f32x4 acc[4][2];
#pragma unroll
    for (int i = 0; i < 4; ++i)
#pragma unroll
        for (int j = 0; j < 2; ++j) acc[i][j] = (f32x4)0.0f;

    // 4 gl16 per wave per stage call (2 chunk-groups x 2 tensors).
    auto stage = [&](int kt, int buf) {
#pragma unroll
        for (int i = 0; i < 2; ++i) {
            const int ch0 = (wid * 2 + i) * 64;       // wave-uniform chunk base
            const int row = (ch0 + lane) >> 3;        // 0..127
            const int gk8 = ((lane & 7) ^ xb(row)) * 8;
            gl16(A + (size_t)(m0 + row) * DM + kt * 64 + gk8, &As[buf][ch0 * 8]);
            gl16(W + (size_t)(n0 + row) * DM + kt * 64 + gk8, &Ws[buf][ch0 * 8]);
        }
    };

    stage(0, 0);
    stage(1, 1);

#pragma unroll
    for (int kt = 0; kt < DM / 64; ++kt) {
        // Wait for tile kt only: its 4 loads were issued before tile kt+1's
        // 4 (in-order vmcnt decrement), so <=4 outstanding => tile kt landed.
        if (kt + 1 < DM / 64) {
            asm volatile("s_waitcnt vmcnt(4)" ::: "memory");
        } else {
            asm volatile("s_waitcnt vmcnt(0)" ::: "memory");
        }
        __builtin_amdgcn_s_barrier();      // all waves: tile kt resident;
        __builtin_amdgcn_sched_barrier(0); // no hoisting of ds_reads above
        // Prefetch tile kt+2 into the buffer compute(kt-1) released (its
        // readers all passed the barrier above).
        if (kt + 2 < DM / 64) stage(kt + 2, (kt + 2) % 3);

        const int cur = kt % 3;
#pragma unroll
        for (int ks = 0; ks < 2; ++ks) {
            s16x8 af[4], bw[2];
#pragma unroll
            for (int rb = 0; rb < 4; ++rb)
                af[rb] = *(const s16x8*)&As[cur][swz(wm*64 + rb*16 + lr, ks*32 + lk*8)];
#pragma unroll
            for (int cb = 0; cb < 2; ++cb)
                bw[cb] = *(const s16x8*)&Ws[cur][swz(wn*32 + cb*16 + lr, ks*32 + lk*8)];
#pragma unroll
            for (int rb = 0; rb < 4; ++rb)
#pragma unroll
                for (int cb = 0; cb < 2; ++cb)
                    acc[rb][cb] = MFMA16(af[rb], bw[cb], acc[rb][cb]);
        }
    }

    // Epilogue.
    const float QSC = 0.125f * 1.44269504f;   // 1/sqrt(64) * log2(e)
#pragma unroll
    for (int cb = 0; cb < 2; ++cb) {
        const int gc = n0 + wn*32 + cb*16 + lr;
        const float bv = bias[gc];
        const int sec = gc >> 9;                 // 0=q 1=k 2=v (wave-uniform)
        const int d = gc & 63;
        const int h = (gc >> 6) & 7;
#pragma unroll
        for (int rb = 0; rb < 4; ++rb) {
            if (sec == 2) {
                // V^T store: 4 consecutive t -> one 8B store at row d.
                const int mj = m0 + wm*64 + rb*16 + lk*4;
                const int b = mj >> 11, tt = mj & 2047;
                const int tkap = (tt & ~15) | (((tt >> 2) & 1) << 3)
                               | (((tt >> 3) & 1) << 2);
                ushort4 v4;
                v4.x = f2bf(acc[rb][cb][0] + bv);
                v4.y = f2bf(acc[rb][cb][1] + bv);
                v4.z = f2bf(acc[rb][cb][2] + bv);
                v4.w = f2bf(acc[rb][cb][3] + bv);
                *(ushort4*)&Vo[((size_t)(b * NH + h) * HD + d) * TT + tkap] = v4;
            } else {
#pragma unroll
                for (int j = 0; j < 4; ++j) {
                    const int m = m0 + wm*64 + rb*16 + lk*4 + j;
                    const int b = m >> 11, t = m & 2047;
                    const float val = acc[rb][cb][j] + bv;
                    const float partner = __shfl_xor(val, 1);
                    const float cs = rcos[t * HD + d];
                    const float sn = rsin[t * HD + d];
                    const float rot = (d & 1) ? partner : -partner;
                    float outv = val * cs + rot * sn;
                    if (sec == 0) outv *= QSC;
                    const unsigned int mb = f2bf(outv);
                    const unsigned int pb = (unsigned int)__shfl_xor((int)mb, 1) & 0xFFFFu;
                    if ((lr & 1) == 0) {        // even-d lane stores the pair
                        unsigned short* dst = (sec == 0) ? Qo : Ko;
                        const size_t idx = (((size_t)(b * NH + h)) * TT + t) * HD + d;
                        *(unsigned int*)&dst[idx] = mb | (pb << 16);
                    }
                }
            }
        }
    }
}

// ---------------------------------------------------------------------------
// Flash attention, SPLIT-K, FIXED-ZERO-MAX softmax: p = exp2(S) directly.
// 8 waves (512 thr): wave (g,p) = q-group g x key-parity p. (r19 verified.)
// NOTE (r20 lesson): 1024-thr/8-wave-EU variant spills (needs ~80 VGPR vs
// 64 cap) -> 4x FETCH from scratch, 4x slower. Keep (512,4): VGPR cap 128.
// ---------------------------------------------------------------------------
__launch_bounds__(512, 4)
__global__ void attn_mfma(const unsigned short* __restrict__ Qb,
                          const unsigned short* __restrict__ Kb,
                          const unsigned short* __restrict__ Vb,
                          unsigned short* __restrict__ At) {
    __shared__ short Ks[2][64 * 128];    // [key&63][(key>>6)*64 + d]; merge scratch
    __shared__ short Vt[2][64 * 128];    // [d][kappa-key]
    __shared__ float lX[4][32];          // parity-1 l per query
    __shared__ float ivX[4][32];         // 1/(l0+l1) per query

    const int tid = threadIdx.x;
    const int lane = tid & 63;
    const int wid = tid >> 6;            // 0..7
    const int g = wid >> 1;              // q-group 0..3
    const int p = wid & 1;               // key parity
    const int q32 = lane & 31;
    const int hi  = lane >> 5;

    // XCD-chunked swizzle: XCD x (= raw%8) gets works x*64..x*64+63 = 4 bh.
    const int raw = blockIdx.x;
    const int work = (raw & 7) * 64 + (raw >> 3);
    const int bh = work >> 4, qt = work & 15;

    const unsigned short* Qg = Qb + (size_t)bh * TT * HD;
    const unsigned short* Kg = Kb + (size_t)bh * TT * HD;
    const unsigned short* Vg = Vb + (size_t)bh * HD * TT;   // V^T layout
    const int qbase = qt * 128 + g * 32;

    // Q as MFMA B-operand (col=q32, k = kk4*16 + hi*8 + j), loop-invariant.
    s16x8 qf[4];
#pragma unroll
    for (int kk4 = 0; kk4 < 4; ++kk4)
        qf[kk4] = *(const s16x8*)(Qg + (size_t)(qbase + q32) * HD + kk4*16 + hi*8);

    // Loop-invariant LDS read offsets (shorts). s = sub - 2p (0 or 1).
    int koff[2][4], voff[2][2][2];
#pragma unroll
    for (int s = 0; s < 2; ++s) {
#pragma unroll
        for (int kk4 = 0; kk4 < 4; ++kk4)
            koff[s][kk4] = swzV(s*32 + q32, p*64 + kk4*16 + hi*8);
#pragma unroll
        for (int kk = 0; kk < 2; ++kk)
#pragma unroll
            for (int db = 0; db < 2; ++db)
                voff[s][kk][db] = swzV(db*32 + q32, (2*p + s)*32 + kk*16 + hi*8);
    }

    f32x16 oacc[2];
    oacc[0] = (f32x16)0.0f;
    oacc[1] = (f32x16)0.0f;
    float lsum = 0.0f;

    auto stageK = [&](int kt, int buf) {
#pragma unroll
        for (int i = 0; i < 2; ++i) {
            const int ch0 = (wid * 2 + i) * 64;       // wave-uniform
            const int idx = ch0 + lane;               // chunk 0..1023
            const int row = idx >> 4;                 // 0..63
            const int gc  = (idx & 15) ^ (row & 15);  // global chunk of row
            const int key = row + ((gc >> 3) << 6);   // keys r / r+64
            const int d8  = (gc & 7) * 8;
            gl16(Kg + (size_t)(kt * KVB + key) * HD + d8, &Ks[buf][ch0 * 8]);
        }
    };
    auto stageV = [&](int kt, int buf) {
#pragma unroll
        for (int i = 0; i < 2; ++i) {
            const int ch0 = (wid * 2 + i) * 64;       // wave-uniform
            const int idx = ch0 + lane;
            const int row = idx >> 4;                 // d 0..63
            const int gc  = (idx & 15) ^ (row & 15);  // global key-chunk
            gl16(Vg + (size_t)row * TT + kt * KVB + gc * 8, &Vt[buf][ch0 * 8]);
        }
    };

    // QK for sub s of this wave's parity: S^T = K Q.
    auto qk = [&](int s, int buf) -> f32x16 {
        f32x16 acc = (f32x16)0.0f;
        __builtin_amdgcn_s_setprio(1);
#pragma unroll
        for (int kk4 = 0; kk4 < 4; ++kk4) {
            const s16x8 kf = *(const s16x8*)&Ks[buf][koff[s][kk4]];
            acc = MFMA32(kf, qf[kk4], acc);
        }
        __builtin_amdgcn_s_setprio(0);
        return acc;
    };

    // softmax (fixed zero max) + pack + PV for sub s.
    auto smpv = [&](const f32x16& sacc, int s, int buf) {
        float pv[16];
#pragma unroll
        for (int r = 0; r < 16; ++r) pv[r] = fexp2(sacc[r]);
        float s8[8];
#pragma unroll
        for (int r = 0; r < 8; ++r) s8[r] = pv[2*r] + pv[2*r+1];
        lsum += ((s8[0]+s8[1]) + (s8[2]+s8[3])) + ((s8[4]+s8[5]) + (s8[6]+s8[7]));

        s16x8 pa[2];
#pragma unroll
        for (int kk = 0; kk < 2; ++kk) {
            unsigned int u0, u1, u2, u3;
            asm("v_cvt_pk_bf16_f32 %0, %1, %2" : "=v"(u0) : "v"(pv[8*kk+0]), "v"(pv[8*kk+1]));
            asm("v_cvt_pk_bf16_f32 %0, %1, %2" : "=v"(u1) : "v"(pv[8*kk+2]), "v"(pv[8*kk+3]));
            asm("v_cvt_pk_bf16_f32 %0, %1, %2" : "=v"(u2) : "v"(pv[8*kk+4]), "v"(pv[8*kk+5]));
            asm("v_cvt_pk_bf16_f32 %0, %1, %2" : "=v"(u3) : "v"(pv[8*kk+6]), "v"(pv[8*kk+7]));
            union { unsigned int u[4]; s16x8 v; } pk;
            pk.u[0] = u0; pk.u[1] = u1; pk.u[2] = u2; pk.u[3] = u3;
            pa[kk] = pk.v;
        }
        __builtin_amdgcn_s_setprio(1);
#pragma unroll
        for (int kk = 0; kk < 2; ++kk)
#pragma unroll
            for (int db = 0; db < 2; ++db) {
                const s16x8 vf = *(const s16x8*)&Vt[buf][voff[s][kk][db]];
                oacc[db] = MFMA32(pa[kk], vf, oacc[db]);
            }
        __builtin_amdgcn_s_setprio(0);
    };

    // Prologue: stage tile 0.
    stageK(0, 0);
    stageV(0, 0);
    __syncthreads();
    int cur = 0;

    for (int kt = 0; kt < NKT; ++kt) {
        const int nxt = cur ^ 1;
        if (kt + 1 < NKT) { stageK(kt + 1, nxt); stageV(kt + 1, nxt); }

        // This wave's parity half: QK(s+1) issued before smpv(s).
        f32x16 sA = qk(0, cur);
        f32x16 sB = qk(1, cur);
        smpv(sA, 0, cur);
        smpv(sB, 1, cur);

        __syncthreads();                   // drains gl16 vmcnt; all waves sync
        cur = nxt;
    }

    // ---- Merge parities: l = l0+l1, O = O0+O1 (exact, same implicit max). ----
    lsum += __shfl_xor(lsum, 32);          // full l for this parity, per-lane q
    float* ex = (float*)Ks;                // 8192 f32 scratch (K reads done)
    if (p == 1) {
        if (lane < 32) lX[g][lane] = lsum;
        float* o = ex + g * 2048;          // r-major [32 rows][64 lanes]
#pragma unroll
        for (int r = 0; r < 16; ++r) {
            o[(2*r)     * 64 + lane] = oacc[0][r];
            o[(2*r + 1) * 64 + lane] = oacc[1][r];
        }
    }
    __syncthreads();
    if (p == 0) {
        if (lane < 32) ivX[g][lane] = 1.0f / (lsum + lX[g][lane]);
        const float* o = ex + g * 2048;
        const int b = bh >> 3, h = bh & 7;
#pragma unroll
        for (int r = 0; r < 16; ++r) {
            const int q = (r & 3) + 8*(r >> 2) + 4*hi;
            const float inv = ivX[g][q];
            const int t = qbase + q;
            unsigned short* dst = At + (size_t)(b * TT + t) * DM + h * HD;
            dst[q32]      = f2bf((oacc[0][r] + o[(2*r)     * 64 + lane]) * inv);
            dst[32 + q32] = f2bf((oacc[1][r] + o[(2*r + 1) * 64 + lane]) * inv);
        }
    }
}

// ---------------------------------------------------------------------------
// Output projection: out = At @ w_out^T + b_out. 64x128 tile, 4 waves,
// DOUBLE-BUFFERED K-loop via global_load_lds.
// ---------------------------------------------------------------------------
__launch_bounds__(256)
__global__ void gemm_out(const unsigned short* __restrict__ A,
                         const unsigned short* __restrict__ W,
                         const float* __restrict__ bias,
                         float* __restrict__ C) {
    __shared__ short As[2][64 * 64];
    __shared__ short Ws[2][128 * 64];

    const int tid = threadIdx.x;
    const int lane = tid & 63;
    const int wid = tid >> 6;
    const int wm = wid >> 1, wn = wid & 1;
    const int lr = lane & 15, lk = lane >> 4;
    const int m0 = blockIdx.y * 64, n0 = blockIdx.x * 128;

    f32x4 acc[2][4];
#pragma unroll
    for (int i = 0; i < 2; ++i)
#pragma unroll
        for (int j = 0; j < 4; ++j) acc[i][j] = (f32x4)0.0f;

    auto stage = [&](int kt, int buf) {
#pragma unroll
        for (int i = 0; i < 2; ++i) {
            const int ch0 = (wid * 2 + i) * 64;
            const int row = (ch0 + lane) >> 3;        // 0..63
            const int gk8 = ((lane & 7) ^ xb(row)) * 8;
            gl16(A + (size_t)(m0 + row) * DM + kt * 64 + gk8, &As[buf][ch0 * 8]);
        }
#pragma unroll
        for (int i = 0; i < 4; ++i) {
            const int ch0 = (wid * 4 + i) * 64;
            const int row = (ch0 + lane) >> 3;        // 0..127
            const int gk8 = ((lane & 7) ^ xb(row)) * 8;
            gl16(W + (size_t)(n0 + row) * DM + kt * 64 + gk8, &Ws[buf][ch0 * 8]);
        }
    };

    stage(0, 0);
    __syncthreads();
    int cur = 0;

    for (int kt = 0; kt < DM / 64; ++kt) {
        const int nxt = cur ^ 1;
        if (kt + 1 < DM / 64) stage(kt + 1, nxt);
#pragma unroll
        for (int ks = 0; ks < 2; ++ks) {
            s16x8 af[2], bw[4];
#pragma unroll
            for (int rb = 0; rb < 2; ++rb)
                af[rb] = *(const s16x8*)&As[cur][swz(wm*32 + rb*16 + lr, ks*32 + lk*8)];
#pragma unroll
            for (int cb = 0; cb < 4; ++cb)
                bw[cb] = *(const s16x8*)&Ws[cur][swz(wn*64 + cb*16 + lr, ks*32 + lk*8)];
#pragma unroll
            for (int rb = 0; rb < 2; ++rb)
#pragma unroll
                for (int cb = 0; cb < 4; ++cb)
                    acc[rb][cb] = MFMA16(af[rb], bw[cb], acc[rb][cb]);
        }
        __syncthreads();
        cur = nxt;
    }

#pragma unroll
    for (int cb = 0; cb < 4; ++cb) {
        const int gc = n0 + wn*64 + cb*16 + lr;
        const float bv = bias[gc];
#pragma unroll
        for (int rb = 0; rb < 2; ++rb) {
#pragma unroll
            for (int j = 0; j < 4; ++j) {
                const int m = m0 + wm*32 + rb*16 + lk*4 + j;
                C[(size_t)m * DM + gc] = acc[rb][cb][j] + bv;
            }
        }
    }
}

extern "C" void kernel_launch(void* const* d_in, const int* in_sizes, int n_in,
                              void* d_out, int out_size, void* d_ws, size_t ws_size,
                              hipStream_t stream) {
    const float* x    = (const float*)d_in[0];
    const float* rsin = (const float*)d_in[1];
    const float* rcos = (const float*)d_in[2];
    const float* wqkv = (const float*)d_in[3];
    const float* bqkv = (const float*)d_in[4];
    const float* wout = (const float*)d_in[5];
    const float* bout = (const float*)d_in[6];
    float* out = (float*)d_out;

    unsigned short* ws16 = (unsigned short*)d_ws;
    const size_t QE = (size_t)4 * NH * TT * HD;          // 4,194,304
    unsigned short* Qbuf = ws16;
    unsigned short* Kbuf = Qbuf + QE;
    unsigned short* Vbuf = Kbuf + QE;                    // V^T [B,H,64,T]
    unsigned short* At   = Vbuf + QE;                    // bf16 [B,T,DM]
    unsigned short* Xb   = At + QE;                      // bf16 x
    unsigned short* Wq   = Xb + (size_t)MM * DM;         // bf16 w_qkv
    unsigned short* Wo   = Wq + (size_t)EQKV * DM;       // bf16 w_out

    cvt3<<<2048, 256, 0, stream>>>(x, Xb, MM * DM / 4,
                                   wqkv, Wq, EQKV * DM / 4,
                                   wout, Wo, DM * DM / 4);

    gemm_qkv<<<dim3(EQKV / 128, MM / 128), 512, 0, stream>>>(
        Xb, Wq, bqkv, rsin, rcos, Qbuf, Kbuf, Vbuf);

    attn_mfma<<<512, 512, 0, stream>>>(Qbuf, Kbuf, Vbuf, At);

    gemm_out<<<dim3(DM / 128, MM / 64), 256, 0, stream>>>(At, Wo, bout, out);
}

// Round 23
// 99.261 us; speedup vs baseline: 1.0781x; 1.0781x over previous
//
#include <hip/hip_runtime.h>
#include <math.h>

// Problem constants (B=4, T=2048, D_MODEL=512, H=8, HD=64)
#define TT   2048
#define DM   512
#define NH   8
#define HD   64
#define MM   8192          // B*T
#define EQKV 1536          // 3*DM
#define KVB  128           // attention key-tile (pair of 64-key parity halves)
#define NKT  (TT / KVB)    // 16

typedef __attribute__((ext_vector_type(4)))  float f32x4;
typedef __attribute__((ext_vector_type(16))) float f32x16;
typedef __attribute__((ext_vector_type(8)))  short s16x8;   // 8 bf16 = 4 VGPRs

#define MFMA16(a, b, c) __builtin_amdgcn_mfma_f32_16x16x32_bf16((a), (b), (c), 0, 0, 0)
#define MFMA32(a, b, c) __builtin_amdgcn_mfma_f32_32x32x16_bf16((a), (b), (c), 0, 0, 0)

__device__ __forceinline__ unsigned short f2bf(float f) {
    unsigned int u = __float_as_uint(f);
    u += 0x7FFFu + ((u >> 16) & 1);          // round-to-nearest-even
    return (unsigned short)(u >> 16);
}

// Hardware 2^x (single v_exp_f32) — libm exp2f expands to a slow precise
// sequence (r7: +17us VALU in attn; r9 confirmed the fix).
__device__ __forceinline__ float fexp2(float x) {
#if __has_builtin(__builtin_amdgcn_exp2f)
    return __builtin_amdgcn_exp2f(x);
#else
    float r; asm("v_exp_f32 %0, %1" : "=v"(r) : "v"(x)); return r;
#endif
}

// chunk XOR bits for [*][64]-short tiles (8 chunks of 8 shorts per row)
__device__ __forceinline__ int xb(int row) {
    return (row & 7) ^ (((row >> 3) & 3) << 1);
}
// swizzled short index, [rows][64] bf16 tile (GEMM staging)
__device__ __forceinline__ int swz(int row, int k) {
    return row * 64 + (k ^ (xb(row) << 3));
}
// swizzled short index, [rows][128] tile, 4-bit XOR -> conflict-free (r10: 0)
__device__ __forceinline__ int swzV(int row, int k) {
    return row * 128 + (k ^ ((row & 15) << 3));
}

// async global->LDS, 16 B per lane; lds base must be wave-uniform.
__device__ __forceinline__ void gl16(const unsigned short* g, short* l) {
    __builtin_amdgcn_global_load_lds(
        (const __attribute__((address_space(1))) unsigned int*)g,
        (__attribute__((address_space(3))) unsigned int*)l, 16, 0, 0);
}

// ---------------------------------------------------------------------------
// fp32 -> bf16 conversion prepass for x, w_qkv, w_out (counts in float4 units)
// ---------------------------------------------------------------------------
__global__ void cvt3(const float* __restrict__ s0, unsigned short* __restrict__ d0, int n0,
                     const float* __restrict__ s1, unsigned short* __restrict__ d1, int n1,
                     const float* __restrict__ s2, unsigned short* __restrict__ d2, int n2) {
    int i = blockIdx.x * blockDim.x + threadIdx.x;
    const int ntot = n0 + n1 + n2;
    const int stride = gridDim.x * blockDim.x;
    for (; i < ntot; i += stride) {
        const float* s; unsigned short* d; int j = i;
        if (j < n0) { s = s0; d = d0; }
        else if (j < n0 + n1) { s = s1; d = d1; j -= n0; }
        else { s = s2; d = d2; j -= n0 + n1; }
        const float4 v = ((const float4*)s)[j];
        ushort4 o;
        o.x = f2bf(v.x); o.y = f2bf(v.y); o.z = f2bf(v.z); o.w = f2bf(v.w);
        ((ushort4*)d)[j] = o;
    }
}

// ---------------------------------------------------------------------------
// QKV projection: qkv = x @ w_qkv^T + b_qkv, fused RoPE + head split.
// Q/K out: bf16 [B,H,T,64] (Q scaled by 0.125*log2e).
// V out: bf16 [B,H,64,T] TRANSPOSED with kappa(t) baked in.
// 128x128 tile, EIGHT waves (512 thr, wave grid 2x4, wave tile 64x32).
// NOTE (r22 lesson): counted-vmcnt 3-buffer pipeline (1 blk/CU) regressed
// to ~49.5us — source-level vmcnt doesn't beat the 2-blk/CU TLP here
// (matches learn_hip m131-m141). Keep the 2-buffer __syncthreads loop.
// ---------------------------------------------------------------------------
__launch_bounds__(512)
__global__ void gemm_qkv(const unsigned short* __restrict__ A,
                         const unsigned short* __restrict__ W,
                         const float* __restrict__ bias,
                         const float* __restrict__ rsin,
                         const float* __restrict__ rcos,
                         unsigned short* __restrict__ Qo,
                         unsigned short* __restrict__ Ko,
                         unsigned short* __restrict__ Vo) {
    __shared__ short As[2][128 * 64];
    __shared__ short Ws[2][128 * 64];

    const int tid = threadIdx.x;
    const int lane = tid & 63;
    const int wid = tid >> 6;            // 0..7
    const int wm = wid >> 2, wn = wid & 3;   // wave tile: rows wm*64, cols wn*32
    const int lr = lane & 15, lk = lane >> 4;
    const int m0 = blockIdx.y * 128, n0 = blockIdx.x * 128;

    f32x4 acc[4][2];
#pragma unroll
    for (int i = 0; i < 4; ++i)
#pragma unroll
        for (int j = 0; j < 2; ++j) acc[i][j] = (f32x4)0.0f;

    auto stage = [&](int kt, int buf) {
#pragma unroll
        for (int i = 0; i < 2; ++i) {
            const int ch0 = (wid * 2 + i) * 64;       // wave-uniform chunk base
            const int row = (ch0 + lane) >> 3;        // 0..127
            const int gk8 = ((lane & 7) ^ xb(row)) * 8;
            gl16(A + (size_t)(m0 + row) * DM + kt * 64 + gk8, &As[buf][ch0 * 8]);
            gl16(W + (size_t)(n0 + row) * DM + kt * 64 + gk8, &Ws[buf][ch0 * 8]);
        }
    };

    stage(0, 0);
    __syncthreads();
    int cur = 0;

    for (int kt = 0; kt < DM / 64; ++kt) {
        const int nxt = cur ^ 1;
        if (kt + 1 < DM / 64) stage(kt + 1, nxt);
#pragma unroll
        for (int ks = 0; ks < 2; ++ks) {
            s16x8 af[4], bw[2];
#pragma unroll
            for (int rb = 0; rb < 4; ++rb)
                af[rb] = *(const s16x8*)&As[cur][swz(wm*64 + rb*16 + lr, ks*32 + lk*8)];
#pragma unroll
            for (int cb = 0; cb < 2; ++cb)
                bw[cb] = *(const s16x8*)&Ws[cur][swz(wn*32 + cb*16 + lr, ks*32 + lk*8)];
#pragma unroll
            for (int rb = 0; rb < 4; ++rb)
#pragma unroll
                for (int cb = 0; cb < 2; ++cb)
                    acc[rb][cb] = MFMA16(af[rb], bw[cb], acc[rb][cb]);
        }
        __syncthreads();                  // drains gl16 vmcnt; next buf ready
        cur = nxt;
    }

    // Epilogue.
    const float QSC = 0.125f * 1.44269504f;   // 1/sqrt(64) * log2(e)
#pragma unroll
    for (int cb = 0; cb < 2; ++cb) {
        const int gc = n0 + wn*32 + cb*16 + lr;
        const float bv = bias[gc];
        const int sec = gc >> 9;                 // 0=q 1=k 2=v (wave-uniform)
        const int d = gc & 63;
        const int h = (gc >> 6) & 7;
#pragma unroll
        for (int rb = 0; rb < 4; ++rb) {
            if (sec == 2) {
                // V^T store: 4 consecutive t -> one 8B store at row d.
                const int mj = m0 + wm*64 + rb*16 + lk*4;
                const int b = mj >> 11, tt = mj & 2047;
                const int tkap = (tt & ~15) | (((tt >> 2) & 1) << 3)
                               | (((tt >> 3) & 1) << 2);
                ushort4 v4;
                v4.x = f2bf(acc[rb][cb][0] + bv);
                v4.y = f2bf(acc[rb][cb][1] + bv);
                v4.z = f2bf(acc[rb][cb][2] + bv);
                v4.w = f2bf(acc[rb][cb][3] + bv);
                *(ushort4*)&Vo[((size_t)(b * NH + h) * HD + d) * TT + tkap] = v4;
            } else {
#pragma unroll
                for (int j = 0; j < 4; ++j) {
                    const int m = m0 + wm*64 + rb*16 + lk*4 + j;
                    const int b = m >> 11, t = m & 2047;
                    const float val = acc[rb][cb][j] + bv;
                    const float partner = __shfl_xor(val, 1);
                    const float cs = rcos[t * HD + d];
                    const float sn = rsin[t * HD + d];
                    const float rot = (d & 1) ? partner : -partner;
                    float outv = val * cs + rot * sn;
                    if (sec == 0) outv *= QSC;
                    const unsigned int mb = f2bf(outv);
                    const unsigned int pb = (unsigned int)__shfl_xor((int)mb, 1) & 0xFFFFu;
                    if ((lr & 1) == 0) {        // even-d lane stores the pair
                        unsigned short* dst = (sec == 0) ? Qo : Ko;
                        const size_t idx = (((size_t)(b * NH + h)) * TT + t) * HD + d;
                        *(unsigned int*)&dst[idx] = mb | (pb << 16);
                    }
                }
            }
        }
    }
}

// ---------------------------------------------------------------------------
// Flash attention, SPLIT-K, FIXED-ZERO-MAX softmax: p = exp2(S) directly.
// 8 waves (512 thr): wave (g,p) = q-group g x key-parity p. (r19 verified.)
// NOTE (r20 lesson): 1024-thr/8-wave-EU variant spills (needs ~80 VGPR vs
// 64 cap) -> 4x FETCH from scratch, 4x slower. Keep (512,4): VGPR cap 128.
// ---------------------------------------------------------------------------
__launch_bounds__(512, 4)
__global__ void attn_mfma(const unsigned short* __restrict__ Qb,
                          const unsigned short* __restrict__ Kb,
                          const unsigned short* __restrict__ Vb,
                          unsigned short* __restrict__ At) {
    __shared__ short Ks[2][64 * 128];    // [key&63][(key>>6)*64 + d]; merge scratch
    __shared__ short Vt[2][64 * 128];    // [d][kappa-key]
    __shared__ float lX[4][32];          // parity-1 l per query
    __shared__ float ivX[4][32];         // 1/(l0+l1) per query

    const int tid = threadIdx.x;
    const int lane = tid & 63;
    const int wid = tid >> 6;            // 0..7
    const int g = wid >> 1;              // q-group 0..3
    const int p = wid & 1;               // key parity
    const int q32 = lane & 31;
    const int hi  = lane >> 5;

    // XCD-chunked swizzle: XCD x (= raw%8) gets works x*64..x*64+63 = 4 bh.
    const int raw = blockIdx.x;
    const int work = (raw & 7) * 64 + (raw >> 3);
    const int bh = work >> 4, qt = work & 15;

    const unsigned short* Qg = Qb + (size_t)bh * TT * HD;
    const unsigned short* Kg = Kb + (size_t)bh * TT * HD;
    const unsigned short* Vg = Vb + (size_t)bh * HD * TT;   // V^T layout
    const int qbase = qt * 128 + g * 32;

    // Q as MFMA B-operand (col=q32, k = kk4*16 + hi*8 + j), loop-invariant.
    s16x8 qf[4];
#pragma unroll
    for (int kk4 = 0; kk4 < 4; ++kk4)
        qf[kk4] = *(const s16x8*)(Qg + (size_t)(qbase + q32) * HD + kk4*16 + hi*8);

    // Loop-invariant LDS read offsets (shorts). s = sub - 2p (0 or 1).
    int koff[2][4], voff[2][2][2];
#pragma unroll
    for (int s = 0; s < 2; ++s) {
#pragma unroll
        for (int kk4 = 0; kk4 < 4; ++kk4)
            koff[s][kk4] = swzV(s*32 + q32, p*64 + kk4*16 + hi*8);
#pragma unroll
        for (int kk = 0; kk < 2; ++kk)
#pragma unroll
            for (int db = 0; db < 2; ++db)
                voff[s][kk][db] = swzV(db*32 + q32, (2*p + s)*32 + kk*16 + hi*8);
    }

    f32x16 oacc[2];
    oacc[0] = (f32x16)0.0f;
    oacc[1] = (f32x16)0.0f;
    float lsum = 0.0f;

    auto stageK = [&](int kt, int buf) {
#pragma unroll
        for (int i = 0; i < 2; ++i) {
            const int ch0 = (wid * 2 + i) * 64;       // wave-uniform
            const int idx = ch0 + lane;               // chunk 0..1023
            const int row = idx >> 4;                 // 0..63
            const int gc  = (idx & 15) ^ (row & 15);  // global chunk of row
            const int key = row + ((gc >> 3) << 6);   // keys r / r+64
            const int d8  = (gc & 7) * 8;
            gl16(Kg + (size_t)(kt * KVB + key) * HD + d8, &Ks[buf][ch0 * 8]);
        }
    };
    auto stageV = [&](int kt, int buf) {
#pragma unroll
        for (int i = 0; i < 2; ++i) {
            const int ch0 = (wid * 2 + i) * 64;       // wave-uniform
            const int idx = ch0 + lane;
            const int row = idx >> 4;                 // d 0..63
            const int gc  = (idx & 15) ^ (row & 15);  // global key-chunk
            gl16(Vg + (size_t)row * TT + kt * KVB + gc * 8, &Vt[buf][ch0 * 8]);
        }
    };

    // QK for sub s of this wave's parity: S^T = K Q.
    auto qk = [&](int s, int buf) -> f32x16 {
        f32x16 acc = (f32x16)0.0f;
        __builtin_amdgcn_s_setprio(1);
#pragma unroll
        for (int kk4 = 0; kk4 < 4; ++kk4) {
            const s16x8 kf = *(const s16x8*)&Ks[buf][koff[s][kk4]];
            acc = MFMA32(kf, qf[kk4], acc);
        }
        __builtin_amdgcn_s_setprio(0);
        return acc;
    };

    // softmax (fixed zero max) + pack + PV for sub s.
    auto smpv = [&](const f32x16& sacc, int s, int buf) {
        float pv[16];
#pragma unroll
        for (int r = 0; r < 16; ++r) pv[r] = fexp2(sacc[r]);
        float s8[8];
#pragma unroll
        for (int r = 0; r < 8; ++r) s8[r] = pv[2*r] + pv[2*r+1];
        lsum += ((s8[0]+s8[1]) + (s8[2]+s8[3])) + ((s8[4]+s8[5]) + (s8[6]+s8[7]));

        s16x8 pa[2];
#pragma unroll
        for (int kk = 0; kk < 2; ++kk) {
            unsigned int u0, u1, u2, u3;
            asm("v_cvt_pk_bf16_f32 %0, %1, %2" : "=v"(u0) : "v"(pv[8*kk+0]), "v"(pv[8*kk+1]));
            asm("v_cvt_pk_bf16_f32 %0, %1, %2" : "=v"(u1) : "v"(pv[8*kk+2]), "v"(pv[8*kk+3]));
            asm("v_cvt_pk_bf16_f32 %0, %1, %2" : "=v"(u2) : "v"(pv[8*kk+4]), "v"(pv[8*kk+5]));
            asm("v_cvt_pk_bf16_f32 %0, %1, %2" : "=v"(u3) : "v"(pv[8*kk+6]), "v"(pv[8*kk+7]));
            union { unsigned int u[4]; s16x8 v; } pk;
            pk.u[0] = u0; pk.u[1] = u1; pk.u[2] = u2; pk.u[3] = u3;
            pa[kk] = pk.v;
        }
        __builtin_amdgcn_s_setprio(1);
#pragma unroll
        for (int kk = 0; kk < 2; ++kk)
#pragma unroll
            for (int db = 0; db < 2; ++db) {
                const s16x8 vf = *(const s16x8*)&Vt[buf][voff[s][kk][db]];
                oacc[db] = MFMA32(pa[kk], vf, oacc[db]);
            }
        __builtin_amdgcn_s_setprio(0);
    };

    // Prologue: stage tile 0.
    stageK(0, 0);
    stageV(0, 0);
    __syncthreads();
    int cur = 0;

    for (int kt = 0; kt < NKT; ++kt) {
        const int nxt = cur ^ 1;
        if (kt + 1 < NKT) { stageK(kt + 1, nxt); stageV(kt + 1, nxt); }

        // This wave's parity half: QK(s+1) issued before smpv(s).
        f32x16 sA = qk(0, cur);
        f32x16 sB = qk(1, cur);
        smpv(sA, 0, cur);
        smpv(sB, 1, cur);

        __syncthreads();                   // drains gl16 vmcnt; all waves sync
        cur = nxt;
    }

    // ---- Merge parities: l = l0+l1, O = O0+O1 (exact, same implicit max). ----
    lsum += __shfl_xor(lsum, 32);          // full l for this parity, per-lane q
    float* ex = (float*)Ks;                // 8192 f32 scratch (K reads done)
    if (p == 1) {
        if (lane < 32) lX[g][lane] = lsum;
        float* o = ex + g * 2048;          // r-major [32 rows][64 lanes]
#pragma unroll
        for (int r = 0; r < 16; ++r) {
            o[(2*r)     * 64 + lane] = oacc[0][r];
            o[(2*r + 1) * 64 + lane] = oacc[1][r];
        }
    }
    __syncthreads();
    if (p == 0) {
        if (lane < 32) ivX[g][lane] = 1.0f / (lsum + lX[g][lane]);
        const float* o = ex + g * 2048;
        const int b = bh >> 3, h = bh & 7;
#pragma unroll
        for (int r = 0; r < 16; ++r) {
            const int q = (r & 3) + 8*(r >> 2) + 4*hi;
            const float inv = ivX[g][q];
            const int t = qbase + q;
            unsigned short* dst = At + (size_t)(b * TT + t) * DM + h * HD;
            dst[q32]      = f2bf((oacc[0][r] + o[(2*r)     * 64 + lane]) * inv);
            dst[32 + q32] = f2bf((oacc[1][r] + o[(2*r + 1) * 64 + lane]) * inv);
        }
    }
}

// ---------------------------------------------------------------------------
// Output projection: out = At @ w_out^T + b_out. 64x128 tile, 4 waves,
// DOUBLE-BUFFERED K-loop via global_load_lds.
// ---------------------------------------------------------------------------
__launch_bounds__(256)
__global__ void gemm_out(const unsigned short* __restrict__ A,
                         const unsigned short* __restrict__ W,
                         const float* __restrict__ bias,
                         float* __restrict__ C) {
    __shared__ short As[2][64 * 64];
    __shared__ short Ws[2][128 * 64];

    const int tid = threadIdx.x;
    const int lane = tid & 63;
    const int wid = tid >> 6;
    const int wm = wid >> 1, wn = wid & 1;
    const int lr = lane & 15, lk = lane >> 4;
    const int m0 = blockIdx.y * 64, n0 = blockIdx.x * 128;

    f32x4 acc[2][4];
#pragma unroll
    for (int i = 0; i < 2; ++i)
#pragma unroll
        for (int j = 0; j < 4; ++j) acc[i][j] = (f32x4)0.0f;

    auto stage = [&](int kt, int buf) {
#pragma unroll
        for (int i = 0; i < 2; ++i) {
            const int ch0 = (wid * 2 + i) * 64;
            const int row = (ch0 + lane) >> 3;        // 0..63
            const int gk8 = ((lane & 7) ^ xb(row)) * 8;
            gl16(A + (size_t)(m0 + row) * DM + kt * 64 + gk8, &As[buf][ch0 * 8]);
        }
#pragma unroll
        for (int i = 0; i < 4; ++i) {
            const int ch0 = (wid * 4 + i) * 64;
            const int row = (ch0 + lane) >> 3;        // 0..127
            const int gk8 = ((lane & 7) ^ xb(row)) * 8;
            gl16(W + (size_t)(n0 + row) * DM + kt * 64 + gk8, &Ws[buf][ch0 * 8]);
        }
    };

    stage(0, 0);
    __syncthreads();
    int cur = 0;

    for (int kt = 0; kt < DM / 64; ++kt) {
        const int nxt = cur ^ 1;
        if (kt + 1 < DM / 64) stage(kt + 1, nxt);
#pragma unroll
        for (int ks = 0; ks < 2; ++ks) {
            s16x8 af[2], bw[4];
#pragma unroll
            for (int rb = 0; rb < 2; ++rb)
                af[rb] = *(const s16x8*)&As[cur][swz(wm*32 + rb*16 + lr, ks*32 + lk*8)];
#pragma unroll
            for (int cb = 0; cb < 4; ++cb)
                bw[cb] = *(const s16x8*)&Ws[cur][swz(wn*64 + cb*16 + lr, ks*32 + lk*8)];
#pragma unroll
            for (int rb = 0; rb < 2; ++rb)
#pragma unroll
                for (int cb = 0; cb < 4; ++cb)
                    acc[rb][cb] = MFMA16(af[rb], bw[cb], acc[rb][cb]);
        }
        __syncthreads();
        cur = nxt;
    }

#pragma unroll
    for (int cb = 0; cb < 4; ++cb) {
        const int gc = n0 + wn*64 + cb*16 + lr;
        const float bv = bias[gc];
#pragma unroll
        for (int rb = 0; rb < 2; ++rb) {
#pragma unroll
            for (int j = 0; j < 4; ++j) {
                const int m = m0 + wm*32 + rb*16 + lk*4 + j;
                C[(size_t)m * DM + gc] = acc[rb][cb][j] + bv;
            }
        }
    }
}

extern "C" void kernel_launch(void* const* d_in, const int* in_sizes, int n_in,
                              void* d_out, int out_size, void* d_ws, size_t ws_size,
                              hipStream_t stream) {
    const float* x    = (const float*)d_in[0];
    const float* rsin = (const float*)d_in[1];
    const float* rcos = (const float*)d_in[2];
    const float* wqkv = (const float*)d_in[3];
    const float* bqkv = (const float*)d_in[4];
    const float* wout = (const float*)d_in[5];
    const float* bout = (const float*)d_in[6];
    float* out = (float*)d_out;

    unsigned short* ws16 = (unsigned short*)d_ws;
    const size_t QE = (size_t)4 * NH * TT * HD;          // 4,194,304
    unsigned short* Qbuf = ws16;
    unsigned short* Kbuf = Qbuf + QE;
    unsigned short* Vbuf = Kbuf + QE;                    // V^T [B,H,64,T]
    unsigned short* At   = Vbuf + QE;                    // bf16 [B,T,DM]
    unsigned short* Xb   = At + QE;                      // bf16 x
    unsigned short* Wq   = Xb + (size_t)MM * DM;         // bf16 w_qkv
    unsigned short* Wo   = Wq + (size_t)EQKV * DM;       // bf16 w_out

    cvt3<<<2048, 256, 0, stream>>>(x, Xb, MM * DM / 4,
                                   wqkv, Wq, EQKV * DM / 4,
                                   wout, Wo, DM * DM / 4);

    gemm_qkv<<<dim3(EQKV / 128, MM / 128), 512, 0, stream>>>(
        Xb, Wq, bqkv, rsin, rcos, Qbuf, Kbuf, Vbuf);

    attn_mfma<<<512, 512, 0, stream>>>(Qbuf, Kbuf, Vbuf, At);

    gemm_out<<<dim3(DM / 128, MM / 64), 256, 0, stream>>>(At, Wo, bout, out);
}